// Round 1
// baseline (714.531 us; speedup 1.0000x reference)
//
#include <hip/hip_runtime.h>
#include <hip/hip_bf16.h>

#define Bdim 256
#define Ddim 1024
#define Hdim 2048
#define Tdim 100
#define BH (Bdim*Hdim)            // 524288
#define M3 ((Tdim-1)*Bdim)        // 25344

#define OUT_MEM ((size_t)BH)                          // mem_rec starts after out0
#define OUT_SPK ((size_t)BH + (size_t)Tdim*2*BH)      // spk_rec after mem_rec

typedef __attribute__((ext_vector_type(8))) short short8;
typedef __attribute__((ext_vector_type(4))) float f32x4;

// ---------------- K1: ns0 = X @ W0 (fp32, computed once) ----------------
__global__ __launch_bounds__(256) void k1_ns0(const float* __restrict__ X,
                                              const float* __restrict__ W0,
                                              float* __restrict__ NS0) {
  __shared__ float As[16][65];
  __shared__ float Bs[16][65];
  int tid = threadIdx.x;
  int tm = tid >> 4, tn = tid & 15;
  int bm = blockIdx.x * 64, bn = blockIdx.y * 64;
  float acc[4][4] = {};
  for (int k0 = 0; k0 < Ddim; k0 += 16) {
    for (int i = tid; i < 64*16; i += 256) {
      int m = i >> 4, k = i & 15;
      As[k][m] = X[(size_t)(bm + m)*Ddim + k0 + k];
    }
    for (int i = tid; i < 16*64; i += 256) {
      int k = i >> 6, n = i & 63;
      Bs[k][n] = W0[(size_t)(k0 + k)*Hdim + bn + n];
    }
    __syncthreads();
    #pragma unroll
    for (int k = 0; k < 16; ++k) {
      float a[4], b[4];
      #pragma unroll
      for (int i = 0; i < 4; ++i) a[i] = As[k][tm*4+i];
      #pragma unroll
      for (int j = 0; j < 4; ++j) b[j] = Bs[k][tn*4+j];
      #pragma unroll
      for (int i = 0; i < 4; ++i)
        #pragma unroll
        for (int j = 0; j < 4; ++j) acc[i][j] = fmaf(a[i], b[j], acc[i][j]);
    }
    __syncthreads();
  }
  for (int i = 0; i < 4; ++i)
    for (int j = 0; j < 4; ++j)
      NS0[(size_t)(bm+tm*4+i)*Hdim + bn + tn*4 + j] = acc[i][j];
}

// ---------------- K2b: W1T[n][k] = bf16(W1[k][n]) ----------------
__global__ __launch_bounds__(256) void k2b_tr(const float* __restrict__ W1,
                                              unsigned short* __restrict__ W1T) {
  __shared__ unsigned short tile[32][33];
  int bk = blockIdx.x*32, bn = blockIdx.y*32;
  int tx = threadIdx.x & 31, ty = threadIdx.x >> 5;
  for (int r = ty; r < 32; r += 8) {
    float f = W1[(size_t)(bk + r)*Hdim + bn + tx];
    __hip_bfloat16 h = __float2bfloat16(f);
    tile[r][tx] = *reinterpret_cast<unsigned short*>(&h);
  }
  __syncthreads();
  for (int r = ty; r < 32; r += 8) {
    W1T[(size_t)(bn + r)*Hdim + bk + tx] = tile[tx][r];
  }
}

// ---------------- K2: layer-0 sim; writes mem0_rec, spk_rec, t=0 zeros, bf16 Z ----------------
__global__ __launch_bounds__(256) void k2_sim(const float* __restrict__ NS0,
                                              float* __restrict__ out,
                                              unsigned short* __restrict__ Zb,
                                              int writeZb) {
  size_t idx = (size_t)blockIdx.x*256 + threadIdx.x;  // b*H + j
  float ns = NS0[idx];
  float* mem = out + OUT_MEM;
  float* spk = out + OUT_SPK;
  mem[idx] = 0.f;          // mem_rec[0][0]
  mem[BH + idx] = 0.f;     // mem_rec[0][1]
  spk[idx] = 0.f;          // spk_rec[0]
  float m = 0.f;
  for (int t = 1; t < Tdim; ++t) {
    m = __fadd_rn(__fmul_rn(0.9f, m), ns);   // match numpy's mul-then-add rounding
    bool sp = m > 1.0f;                       // mthr > 0
    float z = sp ? 1.f : 0.f;
    if (sp) m = 0.f;                          // reset, recorded post-reset
    mem[(size_t)(2*t)*BH + idx] = m;
    spk[(size_t)t*BH + idx] = z;
    if (writeZb)
      Zb[(size_t)(t-1)*BH + idx] = sp ? (unsigned short)0x3F80 : (unsigned short)0;
  }
}

// ---------------- K3: C[25344,2048] = Z @ W1 (bf16 MFMA) ----------------
#define K3_BM 128
#define K3_BN 128
#define K3_BK 32
#define LDT 40   // padded row stride in bf16 elems (80B) to break bank conflicts

template<int AFP32>
__global__ __launch_bounds__(256) void k3_gemm(const void* __restrict__ Asrc,
                                               const unsigned short* __restrict__ BT,
                                               unsigned short* __restrict__ Cout) {
  __shared__ short As[K3_BM*LDT];
  __shared__ short Bs[K3_BN*LDT];
  int tid = threadIdx.x;
  int l = tid & 63;
  int w = tid >> 6;
  int wr = (w >> 1) << 6, wc = (w & 1) << 6;   // wave 2x2 over 128x128, each 64x64
  int lr = l & 15, lg = l >> 4;
  size_t gm = (size_t)blockIdx.x * K3_BM;
  size_t gn = (size_t)blockIdx.y * K3_BN;

  f32x4 acc[4][4] = {};

  for (int k0 = 0; k0 < Hdim; k0 += K3_BK) {
    if (AFP32) {
      // A source: fp32 spike record (0.0/1.0) -> bf16 via compare
      const float* A = (const float*)Asrc;
      #pragma unroll
      for (int it = 0; it < 4; ++it) {
        int li = it*256 + tid;
        int r = li >> 3, kq = li & 7;
        float4 v = *reinterpret_cast<const float4*>(&A[(gm + r)*Hdim + k0 + kq*4]);
        ushort4 p;
        p.x = (v.x != 0.f) ? 0x3F80 : 0;
        p.y = (v.y != 0.f) ? 0x3F80 : 0;
        p.z = (v.z != 0.f) ? 0x3F80 : 0;
        p.w = (v.w != 0.f) ? 0x3F80 : 0;
        *reinterpret_cast<ushort4*>(&As[r*LDT + kq*4]) = p;
      }
    } else {
      // A source: bf16 Z buffer
      const unsigned short* A = (const unsigned short*)Asrc;
      #pragma unroll
      for (int it = 0; it < 2; ++it) {
        int li = it*256 + tid;
        int r = li >> 2, kq = li & 3;
        float4 v = *reinterpret_cast<const float4*>(&A[(gm + r)*Hdim + k0 + kq*8]);
        *reinterpret_cast<float4*>(&As[r*LDT + kq*8]) = v;
      }
    }
    // B: W1T[n][k] bf16, 128 n-rows x 32 k
    #pragma unroll
    for (int it = 0; it < 2; ++it) {
      int li = it*256 + tid;
      int n = li >> 2, kq = li & 3;
      float4 v = *reinterpret_cast<const float4*>(&BT[(gn + n)*Hdim + k0 + kq*8]);
      *reinterpret_cast<float4*>(&Bs[n*LDT + kq*8]) = v;
    }
    __syncthreads();
    short8 af[4], bfr[4];
    #pragma unroll
    for (int mi = 0; mi < 4; ++mi)
      af[mi] = *reinterpret_cast<const short8*>(&As[(wr + mi*16 + lr)*LDT + lg*8]);
    #pragma unroll
    for (int ni = 0; ni < 4; ++ni)
      bfr[ni] = *reinterpret_cast<const short8*>(&Bs[(wc + ni*16 + lr)*LDT + lg*8]);
    #pragma unroll
    for (int mi = 0; mi < 4; ++mi)
      #pragma unroll
      for (int ni = 0; ni < 4; ++ni)
        acc[mi][ni] = __builtin_amdgcn_mfma_f32_16x16x32_bf16(af[mi], bfr[ni], acc[mi][ni], 0, 0, 0);
    __syncthreads();
  }
  // epilogue: C/D layout col=lane&15, row=(lane>>4)*4+q
  #pragma unroll
  for (int mi = 0; mi < 4; ++mi)
    #pragma unroll
    for (int ni = 0; ni < 4; ++ni)
      #pragma unroll
      for (int q = 0; q < 4; ++q) {
        size_t row = gm + wr + mi*16 + lg*4 + q;
        size_t col = gn + wc + ni*16 + lr;
        __hip_bfloat16 h = __float2bfloat16(acc[mi][ni][q]);
        Cout[row*Hdim + col] = *reinterpret_cast<unsigned short*>(&h);
      }
}

// ---------------- K4: temporal recurrence over C -> mem1_rec + out0 ----------------
__global__ __launch_bounds__(256) void k4_rec(const unsigned short* __restrict__ C,
                                              float* __restrict__ out) {
  size_t idx = (size_t)blockIdx.x*256 + threadIdx.x;  // b*H + j
  float s = 0.f, m = 0.f;
  float* mem = out + OUT_MEM;
  for (int t = 1; t < Tdim; ++t) {
    unsigned int u = C[(size_t)(t-1)*BH + idx];
    float c = __uint_as_float(u << 16);   // bf16 -> f32 exact
    s = __fadd_rn(__fmul_rn(0.95f, s), c);
    m = __fadd_rn(__fmul_rn(0.9f, m), s);
    mem[(size_t)(2*t + 1)*BH + idx] = m;  // mem_rec[t][1]
  }
  out[idx] = m;                            // mem1_rec[-1]
}

extern "C" void kernel_launch(void* const* d_in, const int* in_sizes, int n_in,
                              void* d_out, int out_size, void* d_ws, size_t ws_size,
                              hipStream_t stream) {
  const float* X  = (const float*)d_in[0];
  const float* W0 = (const float*)d_in[1];
  const float* W1 = (const float*)d_in[2];
  float* out = (float*)d_out;
  char* ws = (char*)d_ws;

  float*          ns0  = (float*)ws;                                  // 2 MiB
  unsigned short* w1t  = (unsigned short*)(ws + (2ull  << 20));       // 8 MiB
  unsigned short* cbuf = (unsigned short*)(ws + (10ull << 20));       // ~99 MiB
  unsigned short* zb   = (unsigned short*)(ws + (112ull << 20));      // ~99 MiB (optional)
  size_t needZb = (112ull << 20) + (size_t)M3 * Hdim * 2;
  int useZb = (ws_size >= needZb) ? 1 : 0;

  k1_ns0<<<dim3(Bdim/64, Hdim/64), 256, 0, stream>>>(X, W0, ns0);
  k2b_tr<<<dim3(Hdim/32, Hdim/32), 256, 0, stream>>>(W1, w1t);
  k2_sim<<<dim3(BH/256), 256, 0, stream>>>(ns0, out, zb, useZb);
  if (useZb)
    k3_gemm<0><<<dim3(M3/K3_BM, Hdim/K3_BN), 256, 0, stream>>>((const void*)zb, w1t, cbuf);
  else
    k3_gemm<1><<<dim3(M3/K3_BM, Hdim/K3_BN), 256, 0, stream>>>((const void*)(out + OUT_SPK + BH), w1t, cbuf);
  k4_rec<<<dim3(BH/256), 256, 0, stream>>>(cbuf, out);
}